// Round 6
// baseline (197.412 us; speedup 1.0000x reference)
//
#include <hip/hip_runtime.h>

#define BB 8
#define NN 2048
#define VV 64
#define NWAVE 16
#define RPW (NN / NWAVE)   // 128 rows per wave

// ---------------------------------------------------------------------------
// Inputs fp32, output fp32 (verified R4/R5, absmax 7.8e-3).
//
// Closed form: after causal masking row i has two non-structural logits:
//   col 0   : c_i = (h_i.qk_bos)*(h_0.qk_direction)
//   col i-1 : s_i = h_i.qk_previous   (merged into col 0 when i==1)
// remaining (i-1) allowed cols have logit 0, value h_j*wv. With
// S_i = sum_{j=1..i} h_j (per channel), m = max(c,s,0):
//   Z   = e^{c-m} + e^{s-m} + (i-1) e^{-m}
//   out = [e^{c-m} vbos + (e^{s-m}-e^{-m}) h_{i-1} wv + e^{-m} S_i wv] / Z
// Row 0: out = vbos.  Row 1: 2-way softmax over {c_1+s_1, 0}.
//
// R5 lesson: two dependent 512x(1-wave) launches cost ~60us (cold HBM, no
// latency hiding, butterflies in serial loop). This version: ONE launch,
// one 1024-thread block per batch (16 waves on one CU), block-internal
// hierarchical prefix via LDS, dots computed lane=row (no shuffles).
// ---------------------------------------------------------------------------

__global__ __launch_bounds__(1024) void fused_attn(
    const float* __restrict__ h,
    const float* __restrict__ wv_bos,
    const float* __restrict__ wv,
    const float* __restrict__ wo_w,
    const float* __restrict__ qk_direction,
    const float* __restrict__ qk_bos,
    const float* __restrict__ qk_previous,
    float* __restrict__ out)
{
  const int tid  = threadIdx.x;
  const int lane = tid & 63;
  const int w    = tid >> 6;          // wave 0..15
  const int b    = blockIdx.x;        // batch

  __shared__ float  s_seg[NWAVE][VV];   // per-wave segment channel sums
  __shared__ float2 s_dots[NWAVE][RPW]; // per-row (c,s) dot pairs
  __shared__ float  s_qb[VV], s_qp[VV];
  __shared__ float  s_vb[VV];           // vbos = wo_w @ wv_bos
  __shared__ float  s_db;               // h[b,0,:].qk_direction

  if (tid < VV)      s_qb[tid]      = qk_bos[tid];
  else if (tid < 2*VV) s_qp[tid-VV] = qk_previous[tid-VV];
  __syncthreads();

  const float* hb = h + (size_t)b * NN * VV;
  const int r0 = w * RPW;

  // ---- Phase A: per-row dot pairs, lane = row (2 x 64 rows per wave).
  // Each lane reads its whole row (16 float4) and FMAs serially: no
  // cross-lane ops. Wave 0 lane 0 piggybacks db on its row-0 pass.
#pragma unroll
  for (int sb = 0; sb < 2; sb++) {
    const int rr = sb * 64 + lane;                  // row within segment
    const float4* hp = (const float4*)(hb + (size_t)(r0 + rr) * VV);
    float cd = 0.f, sd = 0.f, dd = 0.f;
#pragma unroll
    for (int j = 0; j < 16; j++) {
      const float4 q = hp[j];
      cd = fmaf(q.x, s_qb[4*j+0], cd); sd = fmaf(q.x, s_qp[4*j+0], sd);
      cd = fmaf(q.y, s_qb[4*j+1], cd); sd = fmaf(q.y, s_qp[4*j+1], sd);
      cd = fmaf(q.z, s_qb[4*j+2], cd); sd = fmaf(q.z, s_qp[4*j+2], sd);
      cd = fmaf(q.w, s_qb[4*j+3], cd); sd = fmaf(q.w, s_qp[4*j+3], sd);
      if (w == 0 && sb == 0) {                      // db (only lane 0 used)
        dd = fmaf(q.x, qk_direction[4*j+0], dd);
        dd = fmaf(q.y, qk_direction[4*j+1], dd);
        dd = fmaf(q.z, qk_direction[4*j+2], dd);
        dd = fmaf(q.w, qk_direction[4*j+3], dd);
      }
    }
    s_dots[w][rr] = make_float2(cd, sd);
    if (w == 0 && sb == 0 && lane == 0) s_db = dd;
  }

  // ---- Phase B: segment channel sums, lane = channel, 8-way MLP
  // (h is L2-warm from phase A).
  {
    const float* hp = hb + (size_t)r0 * VV + lane;
    float a0=0.f,a1=0.f,a2=0.f,a3=0.f,a4=0.f,a5=0.f,a6=0.f,a7=0.f;
#pragma unroll
    for (int t = 0; t < RPW; t += 8) {
      a0 += hp[(t+0)*VV]; a1 += hp[(t+1)*VV];
      a2 += hp[(t+2)*VV]; a3 += hp[(t+3)*VV];
      a4 += hp[(t+4)*VV]; a5 += hp[(t+5)*VV];
      a6 += hp[(t+6)*VV]; a7 += hp[(t+7)*VV];
    }
    float s = ((a0+a1)+(a2+a3)) + ((a4+a5)+(a6+a7));
    if (w == 0) s -= hp[0];           // prefix S excludes row 0 (vbos slot)
    s_seg[w][lane] = s;
  }

  // ---- Phase B2: vbos — wave w computes channels 4w..4w+3 (butterfly)
  {
    const float wvb = wv_bos[lane];
#pragma unroll
    for (int u = 0; u < 4; u++) {
      const int ch = w * 4 + u;
      float p = wo_w[(size_t)ch * VV + lane] * wvb;
#pragma unroll
      for (int off = 32; off; off >>= 1) p += __shfl_xor(p, off, 64);
      if (lane == 0) s_vb[ch] = p;
    }
  }
  __syncthreads();

  // ---- Phase C: emit. Base prefix from <=15 LDS segment vectors, then
  // 128-row closed-form loop (dots broadcast from LDS, no shuffles).
  {
    float S = 0.f;
    for (int k = 0; k < w; k++) S += s_seg[k][lane];

    const float vb  = s_vb[lane];
    const float dbb = s_db;
    const float wvc = wv[lane];
    float prev = (w > 0) ? hb[(size_t)(r0 - 1) * VV + lane] : 0.f;

#pragma unroll 4
    for (int t = 0; t < RPW; t++) {
      const int ri = r0 + t;
      const float hv = hb[(size_t)ri * VV + lane];
      if (ri > 0) S += hv;                     // S_i = sum_{j=1..i} h_j
      const float2 d = s_dots[w][t];           // uniform addr -> broadcast
      const float ci = d.x * dbb;
      const float si = d.y;
      float o;
      if (w == 0 && t == 0) {
        o = vb;
      } else if (w == 0 && t == 1) {
        const float l  = ci + si;              // merged logit at col 0
        const float m  = fmaxf(l, 0.f);
        const float e0 = __expf(l - m);
        const float e1 = __expf(-m);
        o = (e0 * vb + e1 * hv * wvc) / (e0 + e1);
      } else {
        const float m  = fmaxf(fmaxf(ci, si), 0.f);
        const float e0 = __expf(ci - m);
        const float es = __expf(si - m);
        const float ew = __expf(-m);
        const float Z  = e0 + es + (float)(ri - 1) * ew;
        o = (e0 * vb + (es - ew) * prev * wvc + ew * S * wvc) / Z;
      }
      out[((size_t)b * NN + ri) * VV + lane] = o;
      prev = hv;
    }
  }
}

extern "C" void kernel_launch(void* const* d_in, const int* in_sizes, int n_in,
                              void* d_out, int out_size, void* d_ws, size_t ws_size,
                              hipStream_t stream)
{
  const float* h       = (const float*)d_in[0];
  // d_in[1] = mask_one, d_in[2] = mask_zero — structural (causal), unused
  const float* wv_bos  = (const float*)d_in[3];
  const float* wv      = (const float*)d_in[4];
  const float* wo_w    = (const float*)d_in[5];
  const float* qk_dir  = (const float*)d_in[6];
  const float* qk_bos  = (const float*)d_in[7];
  const float* qk_prev = (const float*)d_in[8];
  float* outp = (float*)d_out;

  hipLaunchKernelGGL(fused_attn, dim3(BB), dim3(1024), 0, stream,
                     h, wv_bos, wv, wo_w, qk_dir, qk_bos, qk_prev, outp);
}

// Round 7
// 149.246 us; speedup vs baseline: 1.3227x; 1.3227x over previous
//
#include <hip/hip_runtime.h>
#include <hip/hip_cooperative_groups.h>

namespace cg = cooperative_groups;

#define BB 8
#define NN 2048
#define VV 64
#define CHK 64             // rows per block
#define NC (NN / CHK)      // 32 chunks per batch
#define NBLK (BB * NC)     // 256 blocks == 256 CUs

// ---------------------------------------------------------------------------
// Inputs fp32, output fp32 (verified R4-R6, absmax 7.8e-3).
//
// Closed form (R4-verified): after causal masking row i has two
// non-structural logits: col 0 = c_i=(h_i.qk_bos)*(h_0.qk_direction),
// col i-1 = s_i=h_i.qk_previous (merged into col 0 when i==1); the other
// (i-1) allowed cols have logit 0 with value h_j*wv. With
// S_i = sum_{j=1..i} h_j, m = max(c,s,0):
//   Z   = e^{c-m} + e^{s-m} + (i-1) e^{-m}
//   out = [e^{c-m} vbos + (e^{s-m}-e^{-m}) h_{i-1} wv + e^{-m} S_i wv] / Z
// Row 0: vbos.  Row 1: 2-way softmax over {c_1+s_1, 0}.
//
// R6 lesson: 8 blocks = 3% of chip -> 120us. This version: ONE cooperative
// launch, 256 blocks (1/CU). Cross-block prefix via parts[] in d_ws +
// grid.sync(). h streamed from L3/HBM exactly once; chunk rows live in
// registers across the sync; emit loop has zero cross-lane ops.
// ---------------------------------------------------------------------------

__global__ __launch_bounds__(256) void coop_attn(
    const float* __restrict__ h,
    const float* __restrict__ wv_bos,
    const float* __restrict__ wv,
    const float* __restrict__ wo_w,
    const float* __restrict__ qk_direction,
    const float* __restrict__ qk_bos,
    const float* __restrict__ qk_previous,
    float* __restrict__ parts,   // ws: [NBLK][VV]
    float* __restrict__ vbos_g,  // ws: [VV]
    float* __restrict__ db_g,    // ws: [BB]
    float* __restrict__ out)
{
  const int tid  = threadIdx.x;
  const int lane = tid & 63;
  const int w    = tid >> 6;        // wave 0..3
  const int bid  = blockIdx.x;
  const int b    = bid >> 5;        // NC == 32
  const int g    = bid & 31;
  const int r0   = g * CHK;

  __shared__ float  tf[CHK * VV];   // 16 KB tile (persists through sync)
  __shared__ float  s_sub[4][VV];   // per-wave 16-row channel sums
  __shared__ float  s_pdc[4][CHK];  // dot partials (c), per channel-quarter
  __shared__ float  s_pds[4][CHK];  // dot partials (s)
  __shared__ float2 s_dots[CHK];    // combined per-row (c,s)
  __shared__ float  s_base[4][VV];  // prefix-base partials

  const float* hb = h + (size_t)b * NN * VV;

  // ---- A1: stage 64x64 tile -> LDS (coalesced float4) ----
  {
    const float4* src = (const float4*)(hb + (size_t)r0 * VV);
    float4* dst = (float4*)tf;
#pragma unroll
    for (int i = 0; i < 4; i++) {
      const int idx = tid + 256 * i;
      dst[idx] = src[idx];
    }
  }

  // ---- A3: dot partials. wave w = channels 16w..16w+15, lane = row.
  //      Global gather (same lines as A1, L2/L3-hot). Zero shuffles. ----
  {
    const float* qb = qk_bos + 16 * w;       // wave-uniform -> s_load
    const float* qp = qk_previous + 16 * w;
    const float4* rp = (const float4*)(hb + (size_t)(r0 + lane) * VV + 16 * w);
    float cd = 0.f, sd = 0.f;
#pragma unroll
    for (int j = 0; j < 4; j++) {
      const float4 q = rp[j];
      cd = fmaf(q.x, qb[4*j+0], cd); sd = fmaf(q.x, qp[4*j+0], sd);
      cd = fmaf(q.y, qb[4*j+1], cd); sd = fmaf(q.y, qp[4*j+1], sd);
      cd = fmaf(q.z, qb[4*j+2], cd); sd = fmaf(q.z, qp[4*j+2], sd);
      cd = fmaf(q.w, qb[4*j+3], cd); sd = fmaf(q.w, qp[4*j+3], sd);
    }
    s_pdc[w][lane] = cd;
    s_pds[w][lane] = sd;
  }

  // prev for wave 0 of g>0 blocks lives in the previous chunk: prefetch now
  float prev0 = 0.f;
  if (w == 0 && g > 0) prev0 = hb[(size_t)(r0 - 1) * VV + lane];

  __syncthreads();

  // ---- A2: register-cache own rows + channel sums (lane = channel) ----
  float hv[16];
  {
    float s = 0.f;
#pragma unroll
    for (int t = 0; t < 16; t++) {
      hv[t] = tf[(16 * w + t) * VV + lane];  // 2-way bank alias: free
      s += hv[t];
    }
    s_sub[w][lane] = s;
  }

  // ---- A5: db (g==0 blocks, wave 3) and vbos (block 0, all waves) ----
  if (g == 0 && w == 3) {
    float p = tf[lane] * qk_direction[lane];
#pragma unroll
    for (int off = 32; off; off >>= 1) p += __shfl_xor(p, off, 64);
    if (lane == 0) db_g[b] = p;
  }
  if (bid == 0) {
    const float wvb = wv_bos[lane];
#pragma unroll
    for (int u = 0; u < 16; u++) {
      const int oc = 16 * w + u;
      float p = wo_w[(size_t)oc * VV + lane] * wvb;
#pragma unroll
      for (int off = 32; off; off >>= 1) p += __shfl_xor(p, off, 64);
      if (lane == 0) vbos_g[oc] = p;
    }
  }

  __syncthreads();

  // ---- A4: combine dots (wave 0); publish parts (wave 1) ----
  if (w == 0) {
    const float cd = s_pdc[0][lane] + s_pdc[1][lane] + s_pdc[2][lane] + s_pdc[3][lane];
    const float sd = s_pds[0][lane] + s_pds[1][lane] + s_pds[2][lane] + s_pds[3][lane];
    s_dots[lane] = make_float2(cd, sd);
  } else if (w == 1) {
    float s = s_sub[0][lane] + s_sub[1][lane] + s_sub[2][lane] + s_sub[3][lane];
    if (g == 0) s -= tf[lane];               // prefix excludes row 0
    parts[(size_t)bid * VV + lane] = s;
  }

  __threadfence();            // device-scope release for parts/db/vbos
  cg::this_grid().sync();     // grid-wide barrier (cooperative launch)

  // ---- B1: prefix base from prior chunks' parts (4-way wave split) ----
  {
    const float* pb = parts + (size_t)b * NC * VV + lane;
    float s = 0.f, s2 = 0.f;
    int k = w;
    for (; k + 8 <= g; k += 8) {            // 2 loads in flight
      s  += pb[(size_t)k * VV];
      s2 += pb[(size_t)(k + 4) * VV];
    }
    for (; k < g; k += 4) s += pb[(size_t)k * VV];
    s_base[w][lane] = s + s2;
  }
  __syncthreads();

  // ---- B2: emit 16 rows per wave, closed form, registers + LDS only ----
  {
    float S = s_base[0][lane] + s_base[1][lane] + s_base[2][lane] + s_base[3][lane];
    for (int k = 0; k < w; k++) S += s_sub[k][lane];
    if (g == 0 && w > 0) S -= tf[lane];     // row 0 excluded from prefix

    const float vb  = vbos_g[lane];
    const float dbb = db_g[b];
    const float wvc = wv[lane];
    float prev = (w > 0) ? tf[(16 * w - 1) * VV + lane] : prev0;

    const int rbase = r0 + 16 * w;
    float* op = out + ((size_t)b * NN + rbase) * VV + lane;

#pragma unroll
    for (int t = 0; t < 16; t++) {
      const int ri = rbase + t;
      const float hvt = hv[t];
      if (ri > 0) S += hvt;                 // S_i = sum_{j=1..i} h_j
      const float2 d = s_dots[16 * w + t];  // uniform LDS -> broadcast
      const float ci = d.x * dbb;
      const float si = d.y;
      float o;
      if (ri == 0) {
        o = vb;
      } else if (ri == 1) {
        const float l  = ci + si;           // merged logit at col 0
        const float m  = fmaxf(l, 0.f);
        const float e0 = __expf(l - m);
        const float e1 = __expf(-m);
        o = (e0 * vb + e1 * hvt * wvc) / (e0 + e1);
      } else {
        const float m  = fmaxf(fmaxf(ci, si), 0.f);
        const float e0 = __expf(ci - m);
        const float es = __expf(si - m);
        const float ew = __expf(-m);
        const float Z  = e0 + es + (float)(ri - 1) * ew;
        o = (e0 * vb + (es - ew) * prev * wvc + ew * S * wvc) / Z;
      }
      op[(size_t)t * VV] = o;
      prev = hvt;
    }
  }
}

extern "C" void kernel_launch(void* const* d_in, const int* in_sizes, int n_in,
                              void* d_out, int out_size, void* d_ws, size_t ws_size,
                              hipStream_t stream)
{
  const float* h       = (const float*)d_in[0];
  // d_in[1] = mask_one, d_in[2] = mask_zero — structural (causal), unused
  const float* wv_bos  = (const float*)d_in[3];
  const float* wv      = (const float*)d_in[4];
  const float* wo_w    = (const float*)d_in[5];
  const float* qk_dir  = (const float*)d_in[6];
  const float* qk_bos  = (const float*)d_in[7];
  const float* qk_prev = (const float*)d_in[8];
  float* outp = (float*)d_out;

  float* ws    = (float*)d_ws;
  float* parts = ws;                        // NBLK*VV floats = 64 KiB
  float* vbos  = parts + NBLK * VV;         // VV floats
  float* db    = vbos + VV;                 // BB floats

  void* args[] = {
    (void*)&h, (void*)&wv_bos, (void*)&wv, (void*)&wo_w,
    (void*)&qk_dir, (void*)&qk_bos, (void*)&qk_prev,
    (void*)&parts, (void*)&vbos, (void*)&db, (void*)&outp
  };
  hipLaunchCooperativeKernel((void*)coop_attn, dim3(NBLK), dim3(256),
                             args, 0, stream);
}

// Round 8
// 103.285 us; speedup vs baseline: 1.9113x; 1.4450x over previous
//
#include <hip/hip_runtime.h>

#define BB 8
#define NN 2048
#define VV 64
#define CHK 64             // rows per block
#define NC (NN / CHK)      // 32 chunks per batch
#define NBLK (BB * NC)     // 256 blocks

// ---------------------------------------------------------------------------
// Inputs fp32, output fp32 (verified R4-R7, absmax 7.8e-3).
//
// Closed form: after causal masking row i has two non-structural logits:
//   col 0   : c_i = (h_i.qk_bos)*(h_0.qk_direction)
//   col i-1 : s_i = h_i.qk_previous   (merged into col 0 when i==1)
// remaining (i-1) allowed cols have logit 0, value h_j*wv. With
// S_i = sum_{j=1..i} h_j, m = max(c,s,0):
//   Z   = e^{c-m} + e^{s-m} + (i-1) e^{-m}
//   out = [e^{c-m} vbos + (e^{s-m}-e^{-m}) h_{i-1} wv + e^{-m} S_i wv] / Z
// Row 0: vbos.  Row 1: 2-way softmax over {c_1+s_1, 0}.
//
// R7 lesson: cooperative launch costs ~60us/iter (graph-capture fallback) +
// grid.sync ~dozens of us. Two plain kernels instead: kernel boundary gives
// device-scope coherence for ws. 256 blocks x 4 waves each; no shuffles in
// any hot loop.
// ---------------------------------------------------------------------------

// K1: per-chunk dots (c,s) per row, chunk channel sums, vbos, db -> ws.
__global__ __launch_bounds__(256) void k1_pre(
    const float* __restrict__ h,
    const float* __restrict__ wv_bos,
    const float* __restrict__ wo_w,
    const float* __restrict__ qk_direction,
    const float* __restrict__ qk_bos,
    const float* __restrict__ qk_previous,
    float2* __restrict__ dots,   // [BB*NN]
    float*  __restrict__ parts,  // [NBLK][VV]
    float*  __restrict__ vbos_g, // [VV]
    float*  __restrict__ db_g)   // [BB]
{
  const int tid  = threadIdx.x;
  const int lane = tid & 63;
  const int w    = tid >> 6;        // wave 0..3
  const int bid  = blockIdx.x;
  const int b    = bid >> 5;        // NC == 32
  const int g    = bid & 31;
  const int r0   = g * CHK;

  __shared__ float tf[CHK * VV];    // 16 KB tile
  __shared__ float s_sub[4][VV];    // per-wave 16-row channel sums
  __shared__ float s_pdc[4][CHK];   // dot partials (c) per channel-quarter
  __shared__ float s_pds[4][CHK];   // dot partials (s)

  const float* hb = h + (size_t)b * NN * VV;

  // stage 64x64 tile -> LDS (coalesced float4)
  {
    const float4* src = (const float4*)(hb + (size_t)r0 * VV);
    float4* dst = (float4*)tf;
#pragma unroll
    for (int i = 0; i < 4; i++) dst[tid + 256 * i] = src[tid + 256 * i];
  }

  // dot partials: wave w covers channels 16w..16w+15, lane = row.
  // Global gather (same lines as staging, L2-hot). Zero shuffles.
  {
    const float* qb = qk_bos + 16 * w;        // wave-uniform -> scalar loads
    const float* qp = qk_previous + 16 * w;
    const float4* rp = (const float4*)(hb + (size_t)(r0 + lane) * VV + 16 * w);
    float cd = 0.f, sd = 0.f;
#pragma unroll
    for (int j = 0; j < 4; j++) {
      const float4 q = rp[j];
      cd = fmaf(q.x, qb[4*j+0], cd); sd = fmaf(q.x, qp[4*j+0], sd);
      cd = fmaf(q.y, qb[4*j+1], cd); sd = fmaf(q.y, qp[4*j+1], sd);
      cd = fmaf(q.z, qb[4*j+2], cd); sd = fmaf(q.z, qp[4*j+2], sd);
      cd = fmaf(q.w, qb[4*j+3], cd); sd = fmaf(q.w, qp[4*j+3], sd);
    }
    s_pdc[w][lane] = cd;
    s_pds[w][lane] = sd;
  }
  __syncthreads();

  // chunk channel sums: wave w sums its 16 rows from LDS (lane = channel)
  {
    float s = 0.f;
#pragma unroll
    for (int t = 0; t < 16; t++) s += tf[(16 * w + t) * VV + lane];
    s_sub[w][lane] = s;
  }

  // db (g==0 blocks, wave 3): h[b,0,:].qk_direction
  if (g == 0 && w == 3) {
    float p = tf[lane] * qk_direction[lane];
#pragma unroll
    for (int off = 32; off; off >>= 1) p += __shfl_xor(p, off, 64);
    if (lane == 0) db_g[b] = p;
  }
  // vbos (block 0): wave w computes out-channels 16w..16w+15
  if (bid == 0) {
    const float wvb = wv_bos[lane];
#pragma unroll
    for (int u = 0; u < 16; u++) {
      const int oc = 16 * w + u;
      float p = wo_w[(size_t)oc * VV + lane] * wvb;
#pragma unroll
      for (int off = 32; off; off >>= 1) p += __shfl_xor(p, off, 64);
      if (lane == 0) vbos_g[oc] = p;
    }
  }
  __syncthreads();

  // combine + publish
  if (w == 0) {
    const float cd = s_pdc[0][lane] + s_pdc[1][lane] + s_pdc[2][lane] + s_pdc[3][lane];
    const float sd = s_pds[0][lane] + s_pds[1][lane] + s_pds[2][lane] + s_pds[3][lane];
    dots[(size_t)b * NN + r0 + lane] = make_float2(cd, sd);
  } else if (w == 1) {
    float s = s_sub[0][lane] + s_sub[1][lane] + s_sub[2][lane] + s_sub[3][lane];
    if (g == 0) s -= tf[lane];      // prefix excludes row 0 (vbos slot)
    parts[(size_t)bid * VV + lane] = s;
  }
}

// K2: prefix base from parts (wave-split), then closed-form emit.
__global__ __launch_bounds__(256) void k2_emit(
    const float* __restrict__ h,
    const float* __restrict__ wv,
    const float2* __restrict__ dots,
    const float*  __restrict__ parts,
    const float*  __restrict__ vbos_g,
    const float*  __restrict__ db_g,
    float* __restrict__ out)
{
  const int tid  = threadIdx.x;
  const int lane = tid & 63;
  const int w    = tid >> 6;
  const int bid  = blockIdx.x;
  const int b    = bid >> 5;
  const int g    = bid & 31;
  const int r0   = g * CHK;

  __shared__ float s_base[4][VV];
  __shared__ float s_sub[4][VV];
  __shared__ float s_h0[VV];

  const float* hb = h + (size_t)b * NN * VV;

  // B1: base prefix over prior chunks, 4-way wave split, 2 loads in flight
  {
    const float* pb = parts + ((size_t)b * NC) * VV + lane;
    float sA = 0.f, sB = 0.f;
    int k = w;
    for (; k + 8 <= g; k += 8) {
      sA += pb[(size_t)k * VV];
      sB += pb[(size_t)(k + 4) * VV];
    }
    for (; k < g; k += 4) sA += pb[(size_t)k * VV];
    s_base[w][lane] = sA + sB;
  }

  // own 16 rows -> registers (coalesced, independent loads)
  float hv[16];
  const int rbase = r0 + 16 * w;
  {
    float s = 0.f;
#pragma unroll
    for (int t = 0; t < 16; t++) {
      hv[t] = hb[(size_t)(rbase + t) * VV + lane];
      s += hv[t];
    }
    s_sub[w][lane] = s;
  }
  if (g == 0 && tid < VV) s_h0[tid] = hb[tid];          // row 0 (exclusion)
  float prev = (rbase > 0) ? hb[(size_t)(rbase - 1) * VV + lane] : 0.f;
  __syncthreads();

  // running prefix at this wave's first row
  float S = s_base[0][lane] + s_base[1][lane] + s_base[2][lane] + s_base[3][lane];
  for (int k = 0; k < w; k++) S += s_sub[k][lane];
  if (g == 0 && w > 0) S -= s_h0[lane];                 // row 0 excluded

  const float vb  = vbos_g[lane];
  const float dbb = db_g[b];
  const float wvc = wv[lane];
  const float2* dp = dots + (size_t)b * NN + rbase;     // uniform -> broadcast
  float* op = out + ((size_t)b * NN + rbase) * VV + lane;

#pragma unroll
  for (int t = 0; t < 16; t++) {
    const int ri = rbase + t;
    const float hvt = hv[t];
    if (ri > 0) S += hvt;                               // S_i = sum_{j=1..i}
    const float2 d = dp[t];
    const float ci = d.x * dbb;
    const float si = d.y;
    float o;
    if (ri == 0) {
      o = vb;
    } else if (ri == 1) {
      const float l  = ci + si;                         // merged logit, col 0
      const float m  = fmaxf(l, 0.f);
      const float e0 = __expf(l - m);
      const float e1 = __expf(-m);
      o = (e0 * vb + e1 * hvt * wvc) / (e0 + e1);
    } else {
      const float m  = fmaxf(fmaxf(ci, si), 0.f);
      const float e0 = __expf(ci - m);
      const float es = __expf(si - m);
      const float ew = __expf(-m);
      const float Z  = e0 + es + (float)(ri - 1) * ew;
      o = (e0 * vb + (es - ew) * prev * wvc + ew * S * wvc) / Z;
    }
    op[(size_t)t * VV] = o;
    prev = hvt;
  }
}

extern "C" void kernel_launch(void* const* d_in, const int* in_sizes, int n_in,
                              void* d_out, int out_size, void* d_ws, size_t ws_size,
                              hipStream_t stream)
{
  const float* h       = (const float*)d_in[0];
  // d_in[1] = mask_one, d_in[2] = mask_zero — structural (causal), unused
  const float* wv_bos  = (const float*)d_in[3];
  const float* wv      = (const float*)d_in[4];
  const float* wo_w    = (const float*)d_in[5];
  const float* qk_dir  = (const float*)d_in[6];
  const float* qk_bos  = (const float*)d_in[7];
  const float* qk_prev = (const float*)d_in[8];
  float* outp = (float*)d_out;

  float*  ws    = (float*)d_ws;
  float2* dots  = (float2*)ws;                       // BB*NN float2 (128 KiB)
  float*  parts = ws + (size_t)BB * NN * 2;          // NBLK*VV      ( 64 KiB)
  float*  vbos  = parts + (size_t)NBLK * VV;         // VV
  float*  db    = vbos + VV;                         // BB

  hipLaunchKernelGGL(k1_pre, dim3(NBLK), dim3(256), 0, stream,
                     h, wv_bos, wo_w, qk_dir, qk_bos, qk_prev,
                     dots, parts, vbos, db);
  hipLaunchKernelGGL(k2_emit, dim3(NBLK), dim3(256), 0, stream,
                     h, wv, dots, parts, vbos, db, outp);
}

// Round 9
// 98.152 us; speedup vs baseline: 2.0113x; 1.0523x over previous
//
#include <hip/hip_runtime.h>

#define BB 8
#define NN 2048
#define VV 64
#define CHK 64             // rows per block
#define NC (NN / CHK)      // 32 chunks per batch
#define NBLK (BB * NC)     // 256 blocks == CU count

// ---------------------------------------------------------------------------
// Inputs fp32, output fp32 (verified R4-R8, absmax 7.8e-3).
//
// Closed form: after causal masking row i has two non-structural logits:
//   col 0   : c_i = (h_i.qk_bos)*(h_0.qk_direction)
//   col i-1 : s_i = h_i.qk_previous   (merged into col 0 when i==1)
// remaining (i-1) allowed cols have logit 0, value h_j*wv. With
// S_i = sum_{j=1..i} h_j, m = max(c,s,0):
//   Z   = e^{c-m} + e^{s-m} + (i-1) e^{-m}
//   out = [e^{c-m} vbos + (e^{s-m}-e^{-m}) h_{i-1} wv + e^{-m} S_i wv] / Z
// Row 0: vbos.  Row 1: 2-way softmax over {c_1+s_1, 0}.
//
// R8 lesson: kernel side is ~10us, harness floor ~90us. Final form: ONE
// plain launch, 256 blocks x 4 waves. Each block computes its prefix base
// directly from h (L2-resident, 8-deep MLP) -- no workspace, no second
// dispatch, no shuffles in the emit loop.
// ---------------------------------------------------------------------------

__global__ __launch_bounds__(256) void attn_one(
    const float* __restrict__ h,
    const float* __restrict__ wv_bos,
    const float* __restrict__ wv,
    const float* __restrict__ wo_w,
    const float* __restrict__ qk_direction,
    const float* __restrict__ qk_bos,
    const float* __restrict__ qk_previous,
    float* __restrict__ out)
{
  const int tid  = threadIdx.x;
  const int lane = tid & 63;
  const int w    = tid >> 6;        // wave 0..3
  const int bid  = blockIdx.x;
  const int b    = bid >> 5;        // NC == 32
  const int g    = bid & 31;
  const int r0   = g * CHK;

  __shared__ float  tf[CHK * VV];     // 16 KB own tile
  __shared__ float  s_wo[VV * 65];    // wo_w, pad-65 (2-way alias = free)
  __shared__ float  s_wvb[VV];
  __shared__ float  s_pdc[4][CHK];    // dot partials (c) per channel-quarter
  __shared__ float  s_pds[4][CHK];    // dot partials (s)
  __shared__ float  s_pre[4][VV];     // prefix partials (chunk-split)
  __shared__ float  s_sub[4][VV];     // per-wave 16-row sums
  __shared__ float2 s_dots[CHK];      // combined per-row (c,s)
  __shared__ float  s_vb[VV];         // vbos
  __shared__ float  s_db;             // h[b,0,:].qk_direction

  const float* hb = h + (size_t)b * NN * VV;

  // ---- A1: stage own 64x64 tile -> LDS (coalesced float4) ----
  {
    const float4* src = (const float4*)(hb + (size_t)r0 * VV);
    float4* dst = (float4*)tf;
#pragma unroll
    for (int i = 0; i < 4; i++) dst[tid + 256 * i] = src[tid + 256 * i];
  }
  // ---- A2: stage wo_w (16 KB) into padded LDS; stage wv_bos ----
  {
#pragma unroll
    for (int i = 0; i < 16; i++) {
      const int idx = tid + 256 * i;         // = c*64 + k, coalesced
      s_wo[(idx >> 6) * 65 + (idx & 63)] = wo_w[idx];
    }
    if (tid < VV) s_wvb[tid] = wv_bos[tid];
  }
  // ---- A3: dot partials. wave w = channels 16w..16w+15, lane = row ----
  {
    const float* qb = qk_bos + 16 * w;       // wave-uniform -> scalar loads
    const float* qp = qk_previous + 16 * w;
    const float4* rp = (const float4*)(hb + (size_t)(r0 + lane) * VV + 16 * w);
    float cd = 0.f, sd = 0.f;
#pragma unroll
    for (int j = 0; j < 4; j++) {
      const float4 q = rp[j];
      cd = fmaf(q.x, qb[4*j+0], cd); sd = fmaf(q.x, qp[4*j+0], sd);
      cd = fmaf(q.y, qb[4*j+1], cd); sd = fmaf(q.y, qp[4*j+1], sd);
      cd = fmaf(q.z, qb[4*j+2], cd); sd = fmaf(q.z, qp[4*j+2], sd);
      cd = fmaf(q.w, qb[4*j+3], cd); sd = fmaf(q.w, qp[4*j+3], sd);
    }
    s_pdc[w][lane] = cd;
    s_pds[w][lane] = sd;
  }
  // ---- A4: prefix partials — wave w sums chunks k=w,w+4,..<g directly
  //      from h (lane = channel, coalesced, 8 accumulators -> MLP) ----
  {
    float a0=0.f,a1=0.f,a2=0.f,a3=0.f,a4=0.f,a5=0.f,a6=0.f,a7=0.f;
    for (int k = w; k < g; k += 4) {
      const float* cp = hb + (size_t)k * CHK * VV + lane;
#pragma unroll
      for (int t = 0; t < CHK; t += 8) {
        a0 += cp[(t+0)*VV]; a1 += cp[(t+1)*VV];
        a2 += cp[(t+2)*VV]; a3 += cp[(t+3)*VV];
        a4 += cp[(t+4)*VV]; a5 += cp[(t+5)*VV];
        a6 += cp[(t+6)*VV]; a7 += cp[(t+7)*VV];
      }
    }
    s_pre[w][lane] = ((a0+a1)+(a2+a3)) + ((a4+a5)+(a6+a7));
  }
  // prev row for wave 0 (g>0); h0 for exclusion/db (g>0 from global)
  float prev0 = 0.f;
  if (w == 0 && g > 0) prev0 = hb[(size_t)(r0 - 1) * VV + lane];
  float h0v = (g > 0) ? hb[lane] : 0.f;

  __syncthreads();
  if (g == 0) h0v = tf[lane];                // row 0 from own tile

  // ---- B1: own rows -> registers + per-wave sums ----
  float hv[16];
  const int rbase = r0 + 16 * w;
  {
    float s = 0.f;
#pragma unroll
    for (int t = 0; t < 16; t++) {
      hv[t] = tf[(16 * w + t) * VV + lane];  // 2-way bank alias: free
      s += hv[t];
    }
    s_sub[w][lane] = s;
  }
  // ---- B2: per-wave side jobs ----
  if (w == 0) {            // combine dots
    const float cd = s_pdc[0][lane] + s_pdc[1][lane] + s_pdc[2][lane] + s_pdc[3][lane];
    const float sd = s_pds[0][lane] + s_pds[1][lane] + s_pds[2][lane] + s_pds[3][lane];
    s_dots[lane] = make_float2(cd, sd);
  } else if (w == 1) {     // db = h[b,0,:].qk_direction
    float p = h0v * qk_direction[lane];
#pragma unroll
    for (int off = 32; off; off >>= 1) p += __shfl_xor(p, off, 64);
    if (lane == 0) s_db = p;
  } else if (w == 3) {     // vbos: lane = out-channel, serial k over LDS
    const float* row = s_wo + lane * 65;
    float v0=0.f,v1=0.f,v2=0.f,v3=0.f;
#pragma unroll
    for (int k = 0; k < VV; k += 4) {
      v0 = fmaf(row[k+0], s_wvb[k+0], v0);
      v1 = fmaf(row[k+1], s_wvb[k+1], v1);
      v2 = fmaf(row[k+2], s_wvb[k+2], v2);
      v3 = fmaf(row[k+3], s_wvb[k+3], v3);
    }
    s_vb[lane] = (v0+v1) + (v2+v3);
  }
  __syncthreads();

  // ---- C: emit 16 rows per wave, closed form, registers + LDS only ----
  {
    // S = sum of rows 1..rbase-1 (chunk partials + prior waves - row 0)
    float S = s_pre[0][lane] + s_pre[1][lane] + s_pre[2][lane] + s_pre[3][lane];
    for (int k = 0; k < w; k++) S += s_sub[k][lane];
    if (g > 0 || w > 0) S -= h0v;            // row 0 excluded from prefix

    const float vb  = s_vb[lane];
    const float dbb = s_db;
    const float wvc = wv[lane];
    float prev = (w > 0) ? tf[(16 * w - 1) * VV + lane] : prev0;
    float* op = out + ((size_t)b * NN + rbase) * VV + lane;

#pragma unroll
    for (int t = 0; t < 16; t++) {
      const int ri = rbase + t;
      const float hvt = hv[t];
      if (ri > 0) S += hvt;                  // S_i = sum_{j=1..i} h_j
      const float2 d = s_dots[16 * w + t];   // uniform LDS -> broadcast
      const float ci = d.x * dbb;
      const float si = d.y;
      float o;
      if (ri == 0) {
        o = vb;
      } else if (ri == 1) {
        const float l  = ci + si;            // merged logit at col 0
        const float m  = fmaxf(l, 0.f);
        const float e0 = __expf(l - m);
        const float e1 = __expf(-m);
        o = (e0 * vb + e1 * hvt * wvc) / (e0 + e1);
      } else {
        const float m  = fmaxf(fmaxf(ci, si), 0.f);
        const float e0 = __expf(ci - m);
        const float es = __expf(si - m);
        const float ew = __expf(-m);
        const float Z  = e0 + es + (float)(ri - 1) * ew;
        o = (e0 * vb + (es - ew) * prev * wvc + ew * S * wvc) / Z;
      }
      op[(size_t)t * VV] = o;
      prev = hvt;
    }
  }
}

extern "C" void kernel_launch(void* const* d_in, const int* in_sizes, int n_in,
                              void* d_out, int out_size, void* d_ws, size_t ws_size,
                              hipStream_t stream)
{
  const float* h       = (const float*)d_in[0];
  // d_in[1] = mask_one, d_in[2] = mask_zero — structural (causal), unused
  const float* wv_bos  = (const float*)d_in[3];
  const float* wv      = (const float*)d_in[4];
  const float* wo_w    = (const float*)d_in[5];
  const float* qk_dir  = (const float*)d_in[6];
  const float* qk_bos  = (const float*)d_in[7];
  const float* qk_prev = (const float*)d_in[8];
  float* outp = (float*)d_out;

  hipLaunchKernelGGL(attn_one, dim3(NBLK), dim3(256), 0, stream,
                     h, wv_bos, wv, wo_w, qk_dir, qk_bos, qk_prev, outp);
}